// Round 1
// baseline (769.599 us; speedup 1.0000x reference)
//
#include <hip/hip_runtime.h>

using h16 = _Float16;
using h16x4 = __attribute__((ext_vector_type(4))) _Float16;
using h16x8 = __attribute__((ext_vector_type(8))) _Float16;
using f32x4 = __attribute__((ext_vector_type(4))) float;

static constexpr int cB = 16, cT = 1024, cD = 512, cH = 8, cDH = 64, cFF = 2048;
static constexpr int cM = cB * cT;          // 16384 rows
static constexpr int cTP = cT + 2;          // padded time (1026)

// ---- runtime mask-encoding probe: element 1 is always valid (lengths>=512) ----
__device__ __forceinline__ bool mask_val(const void* mb, int idx) {
  const unsigned char* u8 = (const unsigned char*)mb;
  if (u8[1] == 1) return u8[idx] != 0;                  // bool bytes
  const float* f = (const float*)mb;
  if (f[1] == 1.0f) return f[idx] != 0.0f;              // float32
  return ((const int*)mb)[idx] != 0;                    // int32
}

__device__ __forceinline__ void gl_lds16(const h16* g, h16* l) {
  __builtin_amdgcn_global_load_lds(
      (const __attribute__((address_space(1))) unsigned int*)g,
      (__attribute__((address_space(3))) unsigned int*)l, 16, 0, 0);
}

// ---------------- casts / repacks ----------------
__global__ __launch_bounds__(256) void k_cast4(const float* __restrict__ in,
                                               h16* __restrict__ out, int n4) {
  int i = blockIdx.x * 256 + threadIdx.x;
  if (i >= n4) return;
  const float4 f = ((const float4*)in)[i];
  h16x4 o = {(h16)f.x, (h16)f.y, (h16)f.z, (h16)f.w};
  ((h16x4*)out)[i] = o;
}

// conv1_w [FF][D][3] -> W1p [FF][3*D]  (W1p[f][k*D+d] = w[f][d][k])
__global__ __launch_bounds__(256) void k_repack_w1(const float* __restrict__ w,
                                                   h16* __restrict__ out) {
  int i = blockIdx.x * 256 + threadIdx.x;   // i = f*512 + d
  if (i >= cFF * cD) return;
  int f = i >> 9, d = i & 511;
#pragma unroll
  for (int k = 0; k < 3; ++k)
    out[f * (3 * cD) + k * cD + d] = (h16)w[(long)i * 3 + k];
}

// conv2_w [D][FF][3] -> W2p [D][3*FF]  (W2p[o][k*FF+f] = w[o][f][k])
__global__ __launch_bounds__(256) void k_repack_w2(const float* __restrict__ w,
                                                   h16* __restrict__ out) {
  int i = blockIdx.x * 256 + threadIdx.x;   // i = o*2048 + f
  if (i >= cD * cFF) return;
  int o = i >> 11, f = i & 2047;
#pragma unroll
  for (int k = 0; k < 3; ++k)
    out[o * (3 * cFF) + k * cFF + f] = (h16)w[(long)i * 3 + k];
}

// zero boundary rows of padded Xp [B][1026][512] and Hp [B][1026][2048]
__global__ __launch_bounds__(256) void k_zero_pads(h16* __restrict__ xp,
                                                   h16* __restrict__ hp) {
  int i = blockIdx.x * 256 + threadIdx.x;
  if (i < cB * 2 * cD) {
    int b = i / (2 * cD); int rr = (i / cD) & 1; int c = i % cD;
    xp[((long)b * cTP + rr * (cTP - 1)) * cD + c] = (h16)0.f;
  }
  if (i < cB * 2 * cFF) {
    int b = i / (2 * cFF); int rr = (i / cFF) & 1; int c = i % cFF;
    hp[((long)b * cTP + rr * (cTP - 1)) * cFF + c] = (h16)0.f;
  }
}

// ---------------- GEMM: C[M,N] = A[M,K] @ W[N,K]^T (+bias)(relu) ----------------
// A_CONV: A row r starts at (r + 2*(r>>10))*lda (padded [B,1026,lda] buffer, K=3*lda)
// OUT_CONV: C row r written at (r + 2*(r>>10) + 1)*N (padded output, interior rows)
template <bool A_CONV, bool OUT_CONV, bool BIAS, bool RELU, bool OUT_H16>
__global__ __launch_bounds__(256)
void gemm_bt(const h16* __restrict__ A, const h16* __restrict__ W,
             const float* __restrict__ bias, void* __restrict__ Cv,
             int N, int Kd, int lda) {
  __shared__ h16 As[128 * 64];
  __shared__ h16 Bs[128 * 64];
  const int tid = threadIdx.x;
  const int w = tid >> 6, l = tid & 63;
  const int m0 = blockIdx.y * 128, n0 = blockIdx.x * 128;
  const int wm = (w >> 1) * 64, wn = (w & 1) * 64;
  const int lr = l >> 3;              // staging: row within 8-row chunk
  const int lc = (l & 7) * 8;         // staging: col element offset
  const int fr = l & 15;              // frag row/col within 16-tile
  const int fq = (l >> 4) * 8;        // frag k offset

  f32x4 zero4 = {0.f, 0.f, 0.f, 0.f};
  f32x4 acc[4][4];
#pragma unroll
  for (int mi = 0; mi < 4; ++mi)
#pragma unroll
    for (int ni = 0; ni < 4; ++ni) acc[mi][ni] = zero4;

  for (int k0 = 0; k0 < Kd; k0 += 64) {
    __syncthreads();
#pragma unroll
    for (int i = 0; i < 4; ++i) {
      int c = w * 4 + i;
      int ar = m0 + c * 8 + lr;
      long aoff = (long)(ar + (A_CONV ? 2 * (ar >> 10) : 0)) * lda + k0 + lc;
      gl_lds16(A + aoff, &As[c * 512]);
      int br = n0 + c * 8 + lr;
      long boff = (long)br * Kd + k0 + lc;
      gl_lds16(W + boff, &Bs[c * 512]);
    }
    __syncthreads();
#pragma unroll
    for (int kc = 0; kc < 2; ++kc) {
      h16x8 af[4], bfr[4];
#pragma unroll
      for (int mi = 0; mi < 4; ++mi)
        af[mi] = *(const h16x8*)&As[(wm + mi * 16 + fr) * 64 + kc * 32 + fq];
#pragma unroll
      for (int ni = 0; ni < 4; ++ni)
        bfr[ni] = *(const h16x8*)&Bs[(wn + ni * 16 + fr) * 64 + kc * 32 + fq];
#pragma unroll
      for (int mi = 0; mi < 4; ++mi)
#pragma unroll
        for (int ni = 0; ni < 4; ++ni)
          acc[mi][ni] = __builtin_amdgcn_mfma_f32_16x16x32_f16(
              af[mi], bfr[ni], acc[mi][ni], 0, 0, 0);
    }
  }
  // epilogue: D row=(l>>4)*4+reg, col=l&15
#pragma unroll
  for (int mi = 0; mi < 4; ++mi) {
#pragma unroll
    for (int ni = 0; ni < 4; ++ni) {
#pragma unroll
      for (int rr = 0; rr < 4; ++rr) {
        int gr = m0 + wm + mi * 16 + (l >> 4) * 4 + rr;
        int gc = n0 + wn + ni * 16 + fr;
        float v = acc[mi][ni][rr];
        if (BIAS) v += bias[gc];
        if (RELU) v = v > 0.f ? v : 0.f;
        long orow = (long)gr + (OUT_CONV ? (2 * (gr >> 10) + 1) : 0);
        if (OUT_H16) ((h16*)Cv)[orow * N + gc] = (h16)v;
        else         ((float*)Cv)[orow * N + gc] = v;
      }
    }
  }
}

// ---------------- flash attention ----------------
// qkv [B*T][1536] fp16. head-row j: data batch j>>3, head j&7; mask batch j&15;
// output -> attn[(j&15)*1024 + q][ (j>>4)*64 + d ]  (torch view-scramble, faithful)
__global__ __launch_bounds__(256)
void k_attn(const h16* __restrict__ qkv, const void* __restrict__ maskbuf,
            h16* __restrict__ attn_out) {
  __shared__ h16 Ks[32 * 64];     // [key][dh]
  __shared__ h16 Vt[64 * 32];     // [dh][key]
  __shared__ h16 Ps[4][16 * 32];  // per-wave P
  __shared__ float sbias[32];
  const int tid = threadIdx.x, w = tid >> 6, l = tid & 63;
  const int j = blockIdx.y, qt = blockIdx.x;
  const int bd = j >> 3, hd = j & 7, bp = j & 15, hp = j >> 4;
  const int q0 = qt * 64 + w * 16;
  const int fr = l & 15, fq = (l >> 4) * 8;

  h16x8 qf[2];
#pragma unroll
  for (int kc = 0; kc < 2; ++kc)
    qf[kc] = *(const h16x8*)&qkv[(long)((bd << 10) + q0 + fr) * 1536 + hd * 64 + kc * 32 + fq];

  f32x4 zero4 = {0.f, 0.f, 0.f, 0.f};
  f32x4 o[4];
#pragma unroll
  for (int nt = 0; nt < 4; ++nt) o[nt] = zero4;
  float mrow[4], lrow[4];
#pragma unroll
  for (int r = 0; r < 4; ++r) { mrow[r] = -1e30f; lrow[r] = 0.f; }

  for (int k0 = 0; k0 < cT; k0 += 32) {
    __syncthreads();
    {
      int key = tid >> 3, dc = (tid & 7) * 8;
      long base = (long)((bd << 10) + k0 + key) * 1536 + hd * 64;
      h16x8 kv = *(const h16x8*)&qkv[base + 512 + dc];
      *(h16x8*)&Ks[key * 64 + dc] = kv;
      h16x8 vv = *(const h16x8*)&qkv[base + 1024 + dc];
#pragma unroll
      for (int i = 0; i < 8; ++i) Vt[(dc + i) * 32 + key] = vv[i];
      if (tid < 32)
        sbias[tid] = mask_val(maskbuf, bp * cT + k0 + tid) ? 0.f : -1e30f;
    }
    __syncthreads();

    f32x4 S[2];
#pragma unroll
    for (int kt = 0; kt < 2; ++kt) {
      f32x4 s = zero4;
#pragma unroll
      for (int kc = 0; kc < 2; ++kc) {
        h16x8 kf = *(const h16x8*)&Ks[(kt * 16 + fr) * 64 + kc * 32 + fq];
        s = __builtin_amdgcn_mfma_f32_16x16x32_f16(qf[kc], kf, s, 0, 0, 0);
      }
#pragma unroll
      for (int r = 0; r < 4; ++r) s[r] = s[r] * 0.125f + sbias[kt * 16 + fr];
      S[kt] = s;
    }
#pragma unroll
    for (int r = 0; r < 4; ++r) {
      float tm = fmaxf(S[0][r], S[1][r]);
#pragma unroll
      for (int m = 1; m < 16; m <<= 1) tm = fmaxf(tm, __shfl_xor(tm, m));
      float mnew = fmaxf(mrow[r], tm);
      float alpha = __expf(mrow[r] - mnew);
      mrow[r] = mnew;
      float p0 = __expf(S[0][r] - mnew), p1 = __expf(S[1][r] - mnew);
      float rs = p0 + p1;
#pragma unroll
      for (int m = 1; m < 16; m <<= 1) rs += __shfl_xor(rs, m);
      lrow[r] = lrow[r] * alpha + rs;
#pragma unroll
      for (int nt = 0; nt < 4; ++nt) o[nt][r] *= alpha;
      int ql = (l >> 4) * 4 + r;
      Ps[w][ql * 32 + fr] = (h16)p0;
      Ps[w][ql * 32 + 16 + fr] = (h16)p1;
    }
    h16x8 pf = *(const h16x8*)&Ps[w][fr * 32 + fq];
#pragma unroll
    for (int nt = 0; nt < 4; ++nt) {
      h16x8 vf = *(const h16x8*)&Vt[(nt * 16 + fr) * 32 + fq];
      o[nt] = __builtin_amdgcn_mfma_f32_16x16x32_f16(pf, vf, o[nt], 0, 0, 0);
    }
  }
#pragma unroll
  for (int r = 0; r < 4; ++r) {
    float inv = 1.f / lrow[r];
    int q = q0 + (l >> 4) * 4 + r;
    long row = (long)bp * cT + q;
#pragma unroll
    for (int nt = 0; nt < 4; ++nt)
      attn_out[row * cD + hp * 64 + nt * 16 + fr] = (h16)(o[nt][r] * inv);
  }
}

// ---------------- fused residual + LayerNorm + mask ----------------
template <bool WRITE_XP>
__global__ __launch_bounds__(256)
void k_ln(const float* __restrict__ X, const float* __restrict__ R,
          const float* __restrict__ g, const float* __restrict__ bta,
          const void* __restrict__ maskbuf,
          float* __restrict__ outf, h16* __restrict__ xp) {
  const int w = threadIdx.x >> 6, l = threadIdx.x & 63;
  const long row = (long)blockIdx.x * 4 + w;
  const float4* x4 = (const float4*)(X + row * cD);
  const float4* r4 = (const float4*)(R + row * cD);
  float4 a0 = x4[l], a1 = x4[l + 64];
  float4 b0 = r4[l], b1 = r4[l + 64];
  float v[8] = {a0.x + b0.x, a0.y + b0.y, a0.z + b0.z, a0.w + b0.w,
                a1.x + b1.x, a1.y + b1.y, a1.z + b1.z, a1.w + b1.w};
  float s = 0.f;
#pragma unroll
  for (int i = 0; i < 8; ++i) s += v[i];
#pragma unroll
  for (int m = 1; m < 64; m <<= 1) s += __shfl_xor(s, m);
  const float mu = s * (1.f / 512.f);
  float s2 = 0.f;
#pragma unroll
  for (int i = 0; i < 8; ++i) { float d = v[i] - mu; s2 += d * d; }
#pragma unroll
  for (int m = 1; m < 64; m <<= 1) s2 += __shfl_xor(s2, m);
  const float rstd = rsqrtf(s2 * (1.f / 512.f) + 1e-5f);
  const float mv = mask_val(maskbuf, (int)row) ? 1.f : 0.f;
  const float4* g4 = (const float4*)g;
  const float4* t4 = (const float4*)bta;
  float4 g0 = g4[l], g1 = g4[l + 64], t0 = t4[l], t1 = t4[l + 64];
  float4 y0, y1;
  y0.x = ((v[0] - mu) * rstd * g0.x + t0.x) * mv;
  y0.y = ((v[1] - mu) * rstd * g0.y + t0.y) * mv;
  y0.z = ((v[2] - mu) * rstd * g0.z + t0.z) * mv;
  y0.w = ((v[3] - mu) * rstd * g0.w + t0.w) * mv;
  y1.x = ((v[4] - mu) * rstd * g1.x + t1.x) * mv;
  y1.y = ((v[5] - mu) * rstd * g1.y + t1.y) * mv;
  y1.z = ((v[6] - mu) * rstd * g1.z + t1.z) * mv;
  y1.w = ((v[7] - mu) * rstd * g1.w + t1.w) * mv;
  ((float4*)(outf + row * cD))[l] = y0;
  ((float4*)(outf + row * cD))[l + 64] = y1;
  if (WRITE_XP) {
    const long xrow = row + 2 * (row >> 10) + 1;
    h16x4 h0 = {(h16)y0.x, (h16)y0.y, (h16)y0.z, (h16)y0.w};
    h16x4 h1 = {(h16)y1.x, (h16)y1.y, (h16)y1.z, (h16)y1.w};
    ((h16x4*)(xp + xrow * cD))[l] = h0;
    ((h16x4*)(xp + xrow * cD))[l + 64] = h1;
  }
}

extern "C" void kernel_launch(void* const* d_in, const int* in_sizes, int n_in,
                              void* d_out, int out_size, void* d_ws, size_t ws_size,
                              hipStream_t stream) {
  const float* dec   = (const float*)d_in[0];
  const void*  maskb = d_in[1];
  const float* qkv_w = (const float*)d_in[2];
  const float* qkv_b = (const float*)d_in[3];
  const float* o_w   = (const float*)d_in[4];
  const float* ln1g  = (const float*)d_in[5];
  const float* ln1b  = (const float*)d_in[6];
  const float* c1w   = (const float*)d_in[7];
  const float* c1b   = (const float*)d_in[8];
  const float* c2w   = (const float*)d_in[9];
  const float* c2b   = (const float*)d_in[10];
  const float* ln2g  = (const float*)d_in[11];
  const float* ln2b  = (const float*)d_in[12];

  char* p = (char*)d_ws;
  auto alloc = [&](size_t bytes) {
    char* r = p; p += (bytes + 255) & ~(size_t)255; return r;
  };
  h16*   dec_h  = (h16*)alloc((size_t)cM * cD * 2);
  h16*   qkvw_h = (h16*)alloc((size_t)3 * cD * cD * 3 * 2 / 3);   // 1536*512
  h16*   ow_h   = (h16*)alloc((size_t)cD * cD * 2);
  h16*   w1p    = (h16*)alloc((size_t)cFF * 3 * cD * 2);
  h16*   w2p    = (h16*)alloc((size_t)cD * 3 * cFF * 2);
  h16*   qkv_h  = (h16*)alloc((size_t)cM * 1536 * 2);
  h16*   attn_h = (h16*)alloc((size_t)cM * cD * 2);
  float* tmp    = (float*)alloc((size_t)cM * cD * 4);
  float* out1   = (float*)alloc((size_t)cM * cD * 4);
  h16*   xp     = (h16*)alloc((size_t)cB * cTP * cD * 2);
  h16*   hp     = (h16*)alloc((size_t)cB * cTP * cFF * 2);
  (void)ws_size; (void)n_in; (void)in_sizes; (void)out_size;

  // casts / repacks
  k_cast4<<<(cM * cD / 4 + 255) / 256, 256, 0, stream>>>(dec, dec_h, cM * cD / 4);
  k_cast4<<<(1536 * cD / 4 + 255) / 256, 256, 0, stream>>>(qkv_w, qkvw_h, 1536 * cD / 4);
  k_cast4<<<(cD * cD / 4 + 255) / 256, 256, 0, stream>>>(o_w, ow_h, cD * cD / 4);
  k_repack_w1<<<(cFF * cD + 255) / 256, 256, 0, stream>>>(c1w, w1p);
  k_repack_w2<<<(cD * cFF + 255) / 256, 256, 0, stream>>>(c2w, w2p);
  k_zero_pads<<<(cB * 2 * cFF + 255) / 256, 256, 0, stream>>>(xp, hp);

  // QKV projection: [16384,512] @ [1536,512]^T + b -> fp16 [16384,1536]
  gemm_bt<false, false, true, false, true>
      <<<dim3(1536 / 128, cM / 128), 256, 0, stream>>>(dec_h, qkvw_h, qkv_b, qkv_h, 1536, cD, cD);

  // attention
  k_attn<<<dim3(cT / 64, cB * cH), 256, 0, stream>>>(qkv_h, maskb, attn_h);

  // O-projection -> f32 tmp
  gemm_bt<false, false, false, false, false>
      <<<dim3(cD / 128, cM / 128), 256, 0, stream>>>(attn_h, ow_h, nullptr, tmp, cD, cD, cD);

  // LN1: out1 = LN(dec + tmp)*mask  (f32) ; also -> padded fp16 Xp
  k_ln<true><<<cM / 4, 256, 0, stream>>>(dec, tmp, ln1g, ln1b, maskb, out1, xp);

  // conv1 as GEMM: Xp[conv rows] @ W1p^T, +b, relu -> padded fp16 Hp
  gemm_bt<true, true, true, true, true>
      <<<dim3(cFF / 128, cM / 128), 256, 0, stream>>>(xp, w1p, c1b, hp, cFF, 3 * cD, cD);

  // conv2 as GEMM: Hp[conv rows] @ W2p^T, +b -> f32 tmp
  gemm_bt<true, false, true, false, false>
      <<<dim3(cD / 128, cM / 128), 256, 0, stream>>>(hp, w2p, c2b, tmp, cD, 3 * cFF, cFF);

  // LN2 -> d_out
  k_ln<false><<<cM / 4, 256, 0, stream>>>(out1, tmp, ln2g, ln2b, maskb, (float*)d_out, nullptr);
}

// Round 2
// 705.797 us; speedup vs baseline: 1.0904x; 1.0904x over previous
//
#include <hip/hip_runtime.h>

using h16 = _Float16;
using h16x4 = __attribute__((ext_vector_type(4))) _Float16;
using h16x8 = __attribute__((ext_vector_type(8))) _Float16;
using f32x4 = __attribute__((ext_vector_type(4))) float;

static constexpr int cB = 16, cT = 1024, cD = 512, cH = 8, cDH = 64, cFF = 2048;
static constexpr int cM = cB * cT;          // 16384 rows
static constexpr int cTP = cT + 2;          // padded time (1026)

// ---- runtime mask-encoding probe: element 1 is always valid (lengths>=512) ----
__device__ __forceinline__ bool mask_val(const void* mb, int idx) {
  const unsigned char* u8 = (const unsigned char*)mb;
  if (u8[1] == 1) return u8[idx] != 0;                  // bool bytes
  const float* f = (const float*)mb;
  if (f[1] == 1.0f) return f[idx] != 0.0f;              // float32
  return ((const int*)mb)[idx] != 0;                    // int32
}

__device__ __forceinline__ void gl_lds16(const h16* g, h16* l) {
  __builtin_amdgcn_global_load_lds(
      (const __attribute__((address_space(1))) unsigned int*)g,
      (__attribute__((address_space(3))) unsigned int*)l, 16, 0, 0);
}

// ---------------- casts / repacks ----------------
__global__ __launch_bounds__(256) void k_cast4(const float* __restrict__ in,
                                               h16* __restrict__ out, int n4) {
  int i = blockIdx.x * 256 + threadIdx.x;
  if (i >= n4) return;
  const float4 f = ((const float4*)in)[i];
  h16x4 o = {(h16)f.x, (h16)f.y, (h16)f.z, (h16)f.w};
  ((h16x4*)out)[i] = o;
}

// conv1_w [FF][D][3] -> W1p [FF][3*D]  (W1p[f][k*D+d] = w[f][d][k])
__global__ __launch_bounds__(256) void k_repack_w1(const float* __restrict__ w,
                                                   h16* __restrict__ out) {
  int i = blockIdx.x * 256 + threadIdx.x;   // i = f*512 + d
  if (i >= cFF * cD) return;
  int f = i >> 9, d = i & 511;
#pragma unroll
  for (int k = 0; k < 3; ++k)
    out[f * (3 * cD) + k * cD + d] = (h16)w[(long)i * 3 + k];
}

// conv2_w [D][FF][3] -> W2p [D][3*FF]  (W2p[o][k*FF+f] = w[o][f][k])
__global__ __launch_bounds__(256) void k_repack_w2(const float* __restrict__ w,
                                                   h16* __restrict__ out) {
  int i = blockIdx.x * 256 + threadIdx.x;   // i = o*2048 + f
  if (i >= cD * cFF) return;
  int o = i >> 11, f = i & 2047;
#pragma unroll
  for (int k = 0; k < 3; ++k)
    out[o * (3 * cFF) + k * cFF + f] = (h16)w[(long)i * 3 + k];
}

// zero boundary rows of padded Xp [B][1026][512] and Hp [B][1026][2048]
__global__ __launch_bounds__(256) void k_zero_pads(h16* __restrict__ xp,
                                                   h16* __restrict__ hp) {
  int i = blockIdx.x * 256 + threadIdx.x;
  if (i < cB * 2 * cD) {
    int b = i / (2 * cD); int rr = (i / cD) & 1; int c = i % cD;
    xp[((long)b * cTP + rr * (cTP - 1)) * cD + c] = (h16)0.f;
  }
  if (i < cB * 2 * cFF) {
    int b = i / (2 * cFF); int rr = (i / cFF) & 1; int c = i % cFF;
    hp[((long)b * cTP + rr * (cTP - 1)) * cFF + c] = (h16)0.f;
  }
}

// ---------------- GEMM: C[M,N] = A[M,K] @ W[N,K]^T (+bias)(relu) ----------------
// A_CONV: A row r starts at (r + 2*(r>>10))*lda (padded [B,1026,lda] buffer)
// OUT_CONV: C row r written at (r + 2*(r>>10) + 1)*ldc (padded output rows)
// VSCAT: QKV mode — cols >=1024 (V) written transposed to Vg[j][dh][t]
template <bool A_CONV, bool OUT_CONV, bool BIAS, bool RELU, bool OUT_H16, bool VSCAT>
__global__ __launch_bounds__(256)
void gemm_bt(const h16* __restrict__ A, const h16* __restrict__ W,
             const float* __restrict__ bias, void* __restrict__ Cv,
             h16* __restrict__ Vg, int ldc, int Kd, int lda) {
  __shared__ h16 As[128 * 64];
  __shared__ h16 Bs[128 * 64];
  const int tid = threadIdx.x;
  const int w = tid >> 6, l = tid & 63;
  const int m0 = blockIdx.y * 128, n0 = blockIdx.x * 128;
  const int wm = (w >> 1) * 64, wn = (w & 1) * 64;
  const int lr = l >> 3;              // staging: row within 8-row chunk
  const int lc = (l & 7) * 8;         // staging: col element offset
  const int fr = l & 15;              // frag row/col within 16-tile
  const int fq = (l >> 4) * 8;        // frag k offset

  f32x4 zero4 = {0.f, 0.f, 0.f, 0.f};
  f32x4 acc[4][4];
#pragma unroll
  for (int mi = 0; mi < 4; ++mi)
#pragma unroll
    for (int ni = 0; ni < 4; ++ni) acc[mi][ni] = zero4;

  for (int k0 = 0; k0 < Kd; k0 += 64) {
    __syncthreads();
#pragma unroll
    for (int i = 0; i < 4; ++i) {
      int c = w * 4 + i;
      int ar = m0 + c * 8 + lr;
      long aoff = (long)(ar + (A_CONV ? 2 * (ar >> 10) : 0)) * lda + k0 + lc;
      gl_lds16(A + aoff, &As[c * 512]);
      int br = n0 + c * 8 + lr;
      long boff = (long)br * Kd + k0 + lc;
      gl_lds16(W + boff, &Bs[c * 512]);
    }
    __syncthreads();
#pragma unroll
    for (int kc = 0; kc < 2; ++kc) {
      h16x8 af[4], bfr[4];
#pragma unroll
      for (int mi = 0; mi < 4; ++mi)
        af[mi] = *(const h16x8*)&As[(wm + mi * 16 + fr) * 64 + kc * 32 + fq];
#pragma unroll
      for (int ni = 0; ni < 4; ++ni)
        bfr[ni] = *(const h16x8*)&Bs[(wn + ni * 16 + fr) * 64 + kc * 32 + fq];
#pragma unroll
      for (int mi = 0; mi < 4; ++mi)
#pragma unroll
        for (int ni = 0; ni < 4; ++ni)
          acc[mi][ni] = __builtin_amdgcn_mfma_f32_16x16x32_f16(
              af[mi], bfr[ni], acc[mi][ni], 0, 0, 0);
    }
  }
  // epilogue: D row=(l>>4)*4+reg, col=l&15
  if (VSCAT && n0 >= 1024) {
    // V third: write transposed into Vg[j=(b*8+h)][dh][t], vectorized over t
#pragma unroll
    for (int mi = 0; mi < 4; ++mi) {
      int t0 = (m0 + wm + mi * 16 + (l >> 4) * 4) & 1023;
      int jj = ((m0 >> 10) << 3);
#pragma unroll
      for (int ni = 0; ni < 4; ++ni) {
        int gc = n0 + wn + ni * 16 + fr;
        int dh = gc & 63;
        int j2 = jj + ((gc - 1024) >> 6);
        float bb = BIAS ? bias[gc] : 0.f;
        h16x4 v4 = {(h16)(acc[mi][ni][0] + bb), (h16)(acc[mi][ni][1] + bb),
                    (h16)(acc[mi][ni][2] + bb), (h16)(acc[mi][ni][3] + bb)};
        *(h16x4*)&Vg[((long)j2 * 64 + dh) * 1024 + t0] = v4;
      }
    }
  } else {
#pragma unroll
    for (int mi = 0; mi < 4; ++mi) {
#pragma unroll
      for (int ni = 0; ni < 4; ++ni) {
#pragma unroll
        for (int rr = 0; rr < 4; ++rr) {
          int gr = m0 + wm + mi * 16 + (l >> 4) * 4 + rr;
          int gc = n0 + wn + ni * 16 + fr;
          float v = acc[mi][ni][rr];
          if (BIAS) v += bias[gc];
          if (RELU) v = v > 0.f ? v : 0.f;
          long orow = (long)gr + (OUT_CONV ? (2 * (gr >> 10) + 1) : 0);
          if (OUT_H16) ((h16*)Cv)[orow * ldc + gc] = (h16)v;
          else         ((float*)Cv)[orow * ldc + gc] = v;
        }
      }
    }
  }
}

// ---------------- flash attention ----------------
// qk [B*T][1024] fp16 (Q cols 0..511, K cols 512..1023); Vg [128][64][1024].
// head-row j: data batch j>>3, head j&7; mask batch j&15;
// output -> attn[(j&15)*1024 + q][ (j>>4)*64 + d ]  (torch view-scramble)
__global__ __launch_bounds__(256)
void k_attn(const h16* __restrict__ qk, const h16* __restrict__ Vg,
            const void* __restrict__ maskbuf, h16* __restrict__ attn_out) {
  __shared__ h16 Ks[64 * 64];       // [key][dh]
  __shared__ h16 Vt[64 * 64];       // [dh][key]
  __shared__ h16 Ps[4][16 * 66];    // per-wave P, padded stride 66
  __shared__ float sbias[64];
  const int tid = threadIdx.x, w = tid >> 6, l = tid & 63;
  const int j = blockIdx.y, qt = blockIdx.x;
  const int bd = j >> 3, hd = j & 7, bp = j & 15, hp = j >> 4;
  const int fr = l & 15, fq = (l >> 4) * 8;
  const int lr = l >> 3, lc = (l & 7) * 8;

  h16x8 qf[2][2];
#pragma unroll
  for (int sm = 0; sm < 2; ++sm)
#pragma unroll
    for (int kc = 0; kc < 2; ++kc)
      qf[sm][kc] = *(const h16x8*)&qk[
          (long)((bd << 10) + qt * 128 + w * 32 + sm * 16 + fr) * 1024 +
          hd * 64 + kc * 32 + fq];

  f32x4 zero4 = {0.f, 0.f, 0.f, 0.f};
  f32x4 o[2][4];
  float mrow[2][4], lrow[2][4];
#pragma unroll
  for (int sm = 0; sm < 2; ++sm)
#pragma unroll
    for (int nt = 0; nt < 4; ++nt) o[sm][nt] = zero4;
#pragma unroll
  for (int sm = 0; sm < 2; ++sm)
#pragma unroll
    for (int r = 0; r < 4; ++r) { mrow[sm][r] = -1e30f; lrow[sm][r] = 0.f; }

  for (int k0 = 0; k0 < cT; k0 += 64) {
    __syncthreads();
#pragma unroll
    for (int i = 0; i < 2; ++i) {
      int c = w * 2 + i;
      int row = c * 8 + lr;
      gl_lds16(qk + (long)((bd << 10) + k0 + row) * 1024 + 512 + hd * 64 + lc,
               &Ks[c * 512]);
      gl_lds16(Vg + ((long)j * 64 + row) * 1024 + k0 + lc, &Vt[c * 512]);
    }
    if (tid < 64)
      sbias[tid] = mask_val(maskbuf, bp * cT + k0 + tid) ? 0.f : -1e30f;
    __syncthreads();

#pragma unroll
    for (int sm = 0; sm < 2; ++sm) {
      f32x4 S[4];
#pragma unroll
      for (int kt = 0; kt < 4; ++kt) {
        f32x4 s = zero4;
#pragma unroll
        for (int kc = 0; kc < 2; ++kc) {
          h16x8 kf = *(const h16x8*)&Ks[(kt * 16 + fr) * 64 + kc * 32 + fq];
          s = __builtin_amdgcn_mfma_f32_16x16x32_f16(qf[sm][kc], kf, s, 0, 0, 0);
        }
#pragma unroll
        for (int r = 0; r < 4; ++r) s[r] = s[r] * 0.125f + sbias[kt * 16 + fr];
        S[kt] = s;
      }
#pragma unroll
      for (int r = 0; r < 4; ++r) {
        float tm = fmaxf(fmaxf(S[0][r], S[1][r]), fmaxf(S[2][r], S[3][r]));
#pragma unroll
        for (int m = 1; m < 16; m <<= 1) tm = fmaxf(tm, __shfl_xor(tm, m));
        float mnew = fmaxf(mrow[sm][r], tm);
        float alpha = __expf(mrow[sm][r] - mnew);
        mrow[sm][r] = mnew;
        float p[4], rs = 0.f;
#pragma unroll
        for (int kt = 0; kt < 4; ++kt) { p[kt] = __expf(S[kt][r] - mnew); rs += p[kt]; }
#pragma unroll
        for (int m = 1; m < 16; m <<= 1) rs += __shfl_xor(rs, m);
        lrow[sm][r] = lrow[sm][r] * alpha + rs;
#pragma unroll
        for (int nt = 0; nt < 4; ++nt) o[sm][nt][r] *= alpha;
        int ql = (l >> 4) * 4 + r;
#pragma unroll
        for (int kt = 0; kt < 4; ++kt)
          Ps[w][ql * 66 + kt * 16 + fr] = (h16)p[kt];
      }
#pragma unroll
      for (int kp = 0; kp < 2; ++kp) {
        h16x8 pf = *(const h16x8*)&Ps[w][fr * 66 + kp * 32 + fq];
#pragma unroll
        for (int nt = 0; nt < 4; ++nt) {
          h16x8 vf = *(const h16x8*)&Vt[(nt * 16 + fr) * 64 + kp * 32 + fq];
          o[sm][nt] = __builtin_amdgcn_mfma_f32_16x16x32_f16(pf, vf, o[sm][nt], 0, 0, 0);
        }
      }
    }
  }
#pragma unroll
  for (int sm = 0; sm < 2; ++sm) {
#pragma unroll
    for (int r = 0; r < 4; ++r) {
      float inv = 1.f / lrow[sm][r];
      int q = qt * 128 + w * 32 + sm * 16 + (l >> 4) * 4 + r;
      long row = (long)bp * cT + q;
#pragma unroll
      for (int nt = 0; nt < 4; ++nt)
        attn_out[row * cD + hp * 64 + nt * 16 + fr] = (h16)(o[sm][nt][r] * inv);
    }
  }
}

// ---------------- fused residual + LayerNorm + mask ----------------
template <bool WRITE_XP>
__global__ __launch_bounds__(256)
void k_ln(const float* __restrict__ X, const float* __restrict__ R,
          const float* __restrict__ g, const float* __restrict__ bta,
          const void* __restrict__ maskbuf,
          float* __restrict__ outf, h16* __restrict__ xp) {
  const int w = threadIdx.x >> 6, l = threadIdx.x & 63;
  const long row = (long)blockIdx.x * 4 + w;
  const float4* x4 = (const float4*)(X + row * cD);
  const float4* r4 = (const float4*)(R + row * cD);
  float4 a0 = x4[l], a1 = x4[l + 64];
  float4 b0 = r4[l], b1 = r4[l + 64];
  float v[8] = {a0.x + b0.x, a0.y + b0.y, a0.z + b0.z, a0.w + b0.w,
                a1.x + b1.x, a1.y + b1.y, a1.z + b1.z, a1.w + b1.w};
  float s = 0.f;
#pragma unroll
  for (int i = 0; i < 8; ++i) s += v[i];
#pragma unroll
  for (int m = 1; m < 64; m <<= 1) s += __shfl_xor(s, m);
  const float mu = s * (1.f / 512.f);
  float s2 = 0.f;
#pragma unroll
  for (int i = 0; i < 8; ++i) { float d = v[i] - mu; s2 += d * d; }
#pragma unroll
  for (int m = 1; m < 64; m <<= 1) s2 += __shfl_xor(s2, m);
  const float rstd = rsqrtf(s2 * (1.f / 512.f) + 1e-5f);
  const float mv = mask_val(maskbuf, (int)row) ? 1.f : 0.f;
  const float4* g4 = (const float4*)g;
  const float4* t4 = (const float4*)bta;
  float4 g0 = g4[l], g1 = g4[l + 64], t0 = t4[l], t1 = t4[l + 64];
  float4 y0, y1;
  y0.x = ((v[0] - mu) * rstd * g0.x + t0.x) * mv;
  y0.y = ((v[1] - mu) * rstd * g0.y + t0.y) * mv;
  y0.z = ((v[2] - mu) * rstd * g0.z + t0.z) * mv;
  y0.w = ((v[3] - mu) * rstd * g0.w + t0.w) * mv;
  y1.x = ((v[4] - mu) * rstd * g1.x + t1.x) * mv;
  y1.y = ((v[5] - mu) * rstd * g1.y + t1.y) * mv;
  y1.z = ((v[6] - mu) * rstd * g1.z + t1.z) * mv;
  y1.w = ((v[7] - mu) * rstd * g1.w + t1.w) * mv;
  ((float4*)(outf + row * cD))[l] = y0;
  ((float4*)(outf + row * cD))[l + 64] = y1;
  if (WRITE_XP) {
    const long xrow = row + 2 * (row >> 10) + 1;
    h16x4 h0 = {(h16)y0.x, (h16)y0.y, (h16)y0.z, (h16)y0.w};
    h16x4 h1 = {(h16)y1.x, (h16)y1.y, (h16)y1.z, (h16)y1.w};
    ((h16x4*)(xp + xrow * cD))[l] = h0;
    ((h16x4*)(xp + xrow * cD))[l + 64] = h1;
  }
}

extern "C" void kernel_launch(void* const* d_in, const int* in_sizes, int n_in,
                              void* d_out, int out_size, void* d_ws, size_t ws_size,
                              hipStream_t stream) {
  const float* dec   = (const float*)d_in[0];
  const void*  maskb = d_in[1];
  const float* qkv_w = (const float*)d_in[2];
  const float* qkv_b = (const float*)d_in[3];
  const float* o_w   = (const float*)d_in[4];
  const float* ln1g  = (const float*)d_in[5];
  const float* ln1b  = (const float*)d_in[6];
  const float* c1w   = (const float*)d_in[7];
  const float* c1b   = (const float*)d_in[8];
  const float* c2w   = (const float*)d_in[9];
  const float* c2b   = (const float*)d_in[10];
  const float* ln2g  = (const float*)d_in[11];
  const float* ln2b  = (const float*)d_in[12];

  char* p = (char*)d_ws;
  auto alloc = [&](size_t bytes) {
    char* r = p; p += (bytes + 255) & ~(size_t)255; return r;
  };
  h16*   dec_h  = (h16*)alloc((size_t)cM * cD * 2);
  h16*   qkvw_h = (h16*)alloc((size_t)1536 * cD * 2);
  h16*   ow_h   = (h16*)alloc((size_t)cD * cD * 2);
  h16*   w1p    = (h16*)alloc((size_t)cFF * 3 * cD * 2);
  h16*   w2p    = (h16*)alloc((size_t)cD * 3 * cFF * 2);
  h16*   qk_h   = (h16*)alloc((size_t)cM * 1024 * 2);          // Q|K, stride 1024
  h16*   vg     = (h16*)alloc((size_t)cB * cH * cDH * cT * 2); // V^T [128][64][1024]
  h16*   attn_h = (h16*)alloc((size_t)cM * cD * 2);
  float* tmp    = (float*)alloc((size_t)cM * cD * 4);
  float* out1   = (float*)alloc((size_t)cM * cD * 4);
  h16*   xp     = (h16*)alloc((size_t)cB * cTP * cD * 2);
  h16*   hp     = (h16*)alloc((size_t)cB * cTP * cFF * 2);
  (void)ws_size; (void)n_in; (void)in_sizes; (void)out_size;

  // casts / repacks
  k_cast4<<<(cM * cD / 4 + 255) / 256, 256, 0, stream>>>(dec, dec_h, cM * cD / 4);
  k_cast4<<<(1536 * cD / 4 + 255) / 256, 256, 0, stream>>>(qkv_w, qkvw_h, 1536 * cD / 4);
  k_cast4<<<(cD * cD / 4 + 255) / 256, 256, 0, stream>>>(o_w, ow_h, cD * cD / 4);
  k_repack_w1<<<(cFF * cD + 255) / 256, 256, 0, stream>>>(c1w, w1p);
  k_repack_w2<<<(cD * cFF + 255) / 256, 256, 0, stream>>>(c2w, w2p);
  k_zero_pads<<<(cB * 2 * cFF + 255) / 256, 256, 0, stream>>>(xp, hp);

  // QKV projection: Q,K -> qk_h [16384,1024]; V -> Vg transposed
  gemm_bt<false, false, true, false, true, true>
      <<<dim3(12, cM / 128), 256, 0, stream>>>(dec_h, qkvw_h, qkv_b, qk_h, vg, 1024, cD, cD);

  // attention (q-tile 128, kv-tile 64)
  k_attn<<<dim3(cT / 128, cB * cH), 256, 0, stream>>>(qk_h, vg, maskb, attn_h);

  // O-projection -> f32 tmp
  gemm_bt<false, false, false, false, false, false>
      <<<dim3(cD / 128, cM / 128), 256, 0, stream>>>(attn_h, ow_h, nullptr, tmp, nullptr, cD, cD, cD);

  // LN1: out1 = LN(dec + tmp)*mask  (f32) ; also -> padded fp16 Xp
  k_ln<true><<<cM / 4, 256, 0, stream>>>(dec, tmp, ln1g, ln1b, maskb, out1, xp);

  // conv1 as GEMM: Xp[conv rows] @ W1p^T, +b, relu -> padded fp16 Hp
  gemm_bt<true, true, true, true, true, false>
      <<<dim3(cFF / 128, cM / 128), 256, 0, stream>>>(xp, w1p, c1b, hp, nullptr, cFF, 3 * cD, cD);

  // conv2 as GEMM: Hp[conv rows] @ W2p^T, +b -> f32 tmp
  gemm_bt<true, false, true, false, false, false>
      <<<dim3(cD / 128, cM / 128), 256, 0, stream>>>(hp, w2p, c2b, tmp, nullptr, cD, 3 * cFF, cFF);

  // LN2 -> d_out
  k_ln<false><<<cM / 4, 256, 0, stream>>>(out1, tmp, ln2g, ln2b, maskb, (float*)d_out, nullptr);
}